// Round 16
// baseline (398.028 us; speedup 1.0000x reference)
//
#include <hip/hip_runtime.h>
#include <hip/hip_fp16.h>

// GCN layer: out = relu( (D^-1/2 A D^-1/2 x) @ W + b )
// N=50000 nodes, E=800000 edges, C=64 channels, fp32 in/out.
//
// Pipeline (rebuilt on-device every call; fixed-capacity bucket regions).
// The per-bucket counting SORT is eliminated: the gather accumulates directly
// into LDS agg[128][*] via ds_add_f32 (shared-float atomicAdd), so srcs/seg
// arrays, segment padding, scan and LDS-scatter phases all vanish.
//   clearcur:   bcur[] = 0 (tiny kernel; hipMemsetAsync's fill showed 45us in R13)
//   bin:        per-block LDS histogram + per-edge rank, 1 reservation atomic
//               per (block,bucket); writes packed (col_lo<<16|src) u32
//   build_lite: per-bucket histogram -> dis=deg^-1/2 (global) + xsh=half(dis*x);
//               block 0 writes zero row xsh[N]
//   gather:     block = bucket. Zero agg LDS; stream cb edges, 8-deep unrolled
//               (8 xsh rows in flight; tail slots -> sentinel p=N -> zero row,
//               v=0); scale agg by dis[t] (ALL 16 quads/row — R15's bug was
//               scaling only 4); 4 rounds of the R8-proven linear epilogue.
// Float atomics only in LDS (ordering noise ~1e-6 << 1.24e-2 threshold).

#define C_CH 64
#define BW   128        // bucket width in nodes
#define BSH  7          // log2(BW)
#define MAXBUK 512      // >= ceil(N/BW) = 391
#define BIN_CHUNK 2048  // edges per bin block (391 blocks)
#define AST  68         // agg row stride in floats (16B-aligned rows)

// ---- clear bucket cursors ---------------------------------------------------
__global__ void clearcur_kernel(int* __restrict__ bcur, int nbuk) {
    int i = blockIdx.x * blockDim.x + threadIdx.x;
    if (i < nbuk) bcur[i] = 0;
}

// ---- bin: scatter edges into fixed-capacity bucket regions (R14-proven) -----
__global__ void __launch_bounds__(256)
bin_kernel(const int* __restrict__ row, const int* __restrict__ col,
           int* __restrict__ bcur, unsigned* __restrict__ epk,
           int E, int nbuk, int cap) {
    __shared__ int h[MAXBUK];                 // block-local bucket counts
    __shared__ int rb[MAXBUK];                // block's reserved rel-base per bucket
    __shared__ unsigned short rank[BIN_CHUNK];// per-edge local rank
    int tid = threadIdx.x;
    int e0 = blockIdx.x * BIN_CHUNK;
    int cntE = E - e0; if (cntE > BIN_CHUNK) cntE = BIN_CHUNK;

    for (int i = tid; i < nbuk; i += 256) h[i] = 0;
    __syncthreads();

    const int4* col4 = (const int4*)(col + e0);   // e0 is 2048-aligned
    const int4* row4 = (const int4*)(row + e0);
    int cnt4 = cntE >> 2;
    for (int i = tid; i < cnt4; i += 256) {       // pass 1: ranks (int4 loads)
        int4 c = col4[i];
        rank[4*i+0] = (unsigned short)atomicAdd(&h[c.x >> BSH], 1);
        rank[4*i+1] = (unsigned short)atomicAdd(&h[c.y >> BSH], 1);
        rank[4*i+2] = (unsigned short)atomicAdd(&h[c.z >> BSH], 1);
        rank[4*i+3] = (unsigned short)atomicAdd(&h[c.w >> BSH], 1);
    }
    for (int i = (cnt4 << 2) + tid; i < cntE; i += 256)
        rank[i] = (unsigned short)atomicAdd(&h[col[e0 + i] >> BSH], 1);
    __syncthreads();

    for (int i = tid; i < nbuk; i += 256)         // 1 atomic/(block,bucket)
        rb[i] = h[i] ? atomicAdd(&bcur[i], h[i]) : 0;   // bcur starts at 0
    __syncthreads();

    for (int i = tid; i < cnt4; i += 256) {       // pass 2: write packed edges
        int4 c = col4[i];
        int4 r = row4[i];
        #pragma unroll
        for (int j = 0; j < 4; ++j) {
            int cc = (j == 0) ? c.x : (j == 1) ? c.y : (j == 2) ? c.z : c.w;
            int rr = (j == 0) ? r.x : (j == 1) ? r.y : (j == 2) ? r.z : r.w;
            int bkt = cc >> BSH;
            int rel = rb[bkt] + (int)rank[4*i+j];
            if (rel < cap)                        // safety clamp (never hit here)
                epk[bkt * cap + rel] = ((unsigned)(cc & (BW - 1)) << 16) | (unsigned)rr;
        }
    }
    for (int i = (cnt4 << 2) + tid; i < cntE; i += 256) {
        int cc = col[e0 + i];
        int bkt = cc >> BSH;
        int rel = rb[bkt] + (int)rank[i];
        if (rel < cap)
            epk[bkt * cap + rel] = ((unsigned)(cc & (BW - 1)) << 16) | (unsigned)row[e0 + i];
    }
}

// ---- build_lite: histogram -> dis + xsh (no sort) ----------------------------
__global__ void __launch_bounds__(256)
build_lite_kernel(const unsigned* __restrict__ epk, const int* __restrict__ bcur,
                  const float* __restrict__ x,
                  float* __restrict__ dis, __half* __restrict__ xsh,
                  int N, int cap) {
    __shared__ int cnt[BW];
    __shared__ float dv[BW];
    int tid = threadIdx.x;
    int b   = blockIdx.x;
    int base = b * cap;
    int cb = bcur[b]; if (cb > cap) cb = cap;
    int nb0 = b << BSH;
    int nn  = N - nb0; if (nn > BW) nn = BW;

    if (tid < BW) cnt[tid] = 0;
    __syncthreads();
    for (int i = tid; i < cb; i += 256)
        atomicAdd(&cnt[(epk[base + i] >> 16) & (BW - 1)], 1);
    __syncthreads();
    if (tid < nn) {
        int d = cnt[tid];
        float di = (d > 0) ? rsqrtf((float)d) : 0.0f;
        dv[tid] = di;
        dis[nb0 + tid] = di;
    }
    __syncthreads();

    // xsh[n][c] = half(dis[n] * x[n][c]) for this bucket's nodes
    int tot2 = nn * (C_CH / 2);
    const float2* x2 = (const float2*)x;
    __half2* o2 = (__half2*)xsh;
    for (int i = tid; i < tot2; i += 256) {
        int nl = i >> 5;
        int c2 = i & 31;
        long long gi = (long long)(nb0 + nl) * (C_CH / 2) + c2;
        float2 v = x2[gi];
        float dn = dv[nl];
        o2[gi] = __floats2half2_rn(v.x * dn, v.y * dn);
    }
    // zero row at index N (gather's sentinel target)
    if (b == 0 && tid < C_CH / 2)
        o2[(long long)N * (C_CH / 2) + tid] = __floats2half2_rn(0.0f, 0.0f);
}

// ---- gather: per-bucket LDS accumulation + linear + ReLU ---------------------
// Block = bucket (128 nodes). Wave = 4 groups x 16 lanes; lane c4 owns channels
// [4c4..4c4+3]. Per iteration each group processes 8 edges: 8 uniform epk
// loads (broadcast within group) + 8 independent xsh row loads in flight, then
// 4 shared-float atomicAdds per edge-lane (ds_add_f32). Tail slots get the
// sentinel p=N (v=0, src=N -> zero row) - branchless. After scaling by dis[t]
// (all 16 quads per row!), groups run 4 rounds of the R8-proven linear epilogue.
__global__ void __launch_bounds__(512)
gather_kernel(const uint2* __restrict__ xsh8,    // [(N+1)][16] x 8B
              const unsigned* __restrict__ epk,
              const int* __restrict__ bcur,
              const float* __restrict__ dis,
              const float* __restrict__ W, const float* __restrict__ bvec,
              float* __restrict__ out, int N, int cap) {
    __shared__ float Ws[C_CH * C_CH];            // 16 KB
    __shared__ float bs[C_CH];
    __shared__ float agg[BW][AST];               // 34.8 KB, 16B-aligned rows

    int tid = threadIdx.x;
    {   // stage W as float4
        const float4* W4 = (const float4*)W;
        float4* Ws4 = (float4*)Ws;
        for (int i = tid; i < C_CH * C_CH / 4; i += 512) Ws4[i] = W4[i];
        if (tid < C_CH) bs[tid] = bvec[tid];
    }
    {   // zero agg (including pad words)
        float* af = &agg[0][0];
        for (int i = tid; i < BW * AST; i += 512) af[i] = 0.0f;
    }
    __syncthreads();

    int b = blockIdx.x;
    int base = b * cap;
    int cb = bcur[b]; if (cb > cap) cb = cap;
    int nb0 = b << BSH;
    int nn  = N - nb0; if (nn > BW) nn = BW;

    int wid  = tid >> 6;      // wave 0..7
    int lane = tid & 63;
    int grp  = lane >> 4;     // edge sub-group 0..3
    int c4   = lane & 15;     // channel quad

    for (int i0 = wid * 32; i0 < cb; i0 += 256) { // 8 waves x 32 edges
        int ib = i0 + grp * 8;
        unsigned p[8];
        #pragma unroll
        for (int k = 0; k < 8; ++k) {             // uniform-per-group loads
            int idx = ib + k;                     // may overread <=31 words (slack alloc'd)
            unsigned pr = epk[base + idx];
            p[k] = (idx < cb) ? pr : (unsigned)N; // sentinel: v=0, src=N (zero row)
        }
        uint2 u[8];
        #pragma unroll
        for (int k = 0; k < 8; ++k) {             // 8 row-loads in flight
            int s = (int)(p[k] & 0xFFFFu);
            u[k] = xsh8[s * 16 + c4];
        }
        #pragma unroll
        for (int k = 0; k < 8; ++k) {
            int v = (int)(p[k] >> 16) & (BW - 1);
            float2 f0 = __half22float2(*(__half2*)&u[k].x);
            float2 f1 = __half22float2(*(__half2*)&u[k].y);
            float* r = &agg[v][4 * c4];
            atomicAdd(r + 0, f0.x);               // ds_add_f32
            atomicAdd(r + 1, f0.y);
            atomicAdd(r + 2, f1.x);
            atomicAdd(r + 3, f1.y);
        }
    }
    __syncthreads();

    // scale agg[v] by dis[nb0+v] : 128 nodes x 16 quads = 2048 quads,
    // 4 per thread (R15 bug: only 4 of 16 quads/row were scaled)
    for (int i = tid; i < BW * 16; i += 512) {
        int v = i >> 4, q = i & 15;
        if (v < nn) {
            float dt = dis[nb0 + v];
            float4* a4 = (float4*)&agg[v][4 * q];
            float4 a = *a4;
            a.x *= dt; a.y *= dt; a.z *= dt; a.w *= dt;
            *a4 = a;
        }
    }
    __syncthreads();

    // linear epilogue: group g handles nodes g, g+32, g+64, g+96
    int g = tid >> 4;
    #pragma unroll 1                              // keep register pressure flat (R10)
    for (int rrd = 0; rrd < 4; ++rrd) {
        int v = g + 32 * rrd;
        if (v < nn) {
            float4 o = *(const float4*)&bs[4 * c4];
            #pragma unroll
            for (int kq = 0; kq < C_CH / 4; ++kq) {
                float4 a4 = *(const float4*)&agg[v][4 * kq];
                float4 w0 = *(const float4*)&Ws[(4 * kq + 0) * C_CH + 4 * c4];
                float4 w1 = *(const float4*)&Ws[(4 * kq + 1) * C_CH + 4 * c4];
                float4 w2 = *(const float4*)&Ws[(4 * kq + 2) * C_CH + 4 * c4];
                float4 w3 = *(const float4*)&Ws[(4 * kq + 3) * C_CH + 4 * c4];
                o.x = fmaf(a4.x, w0.x, o.x); o.y = fmaf(a4.x, w0.y, o.y);
                o.z = fmaf(a4.x, w0.z, o.z); o.w = fmaf(a4.x, w0.w, o.w);
                o.x = fmaf(a4.y, w1.x, o.x); o.y = fmaf(a4.y, w1.y, o.y);
                o.z = fmaf(a4.y, w1.z, o.z); o.w = fmaf(a4.y, w1.w, o.w);
                o.x = fmaf(a4.z, w2.x, o.x); o.y = fmaf(a4.z, w2.y, o.y);
                o.z = fmaf(a4.z, w2.z, o.z); o.w = fmaf(a4.z, w2.w, o.w);
                o.x = fmaf(a4.w, w3.x, o.x); o.y = fmaf(a4.w, w3.y, o.y);
                o.z = fmaf(a4.w, w3.z, o.z); o.w = fmaf(a4.w, w3.w, o.w);
            }
            o.x = fmaxf(o.x, 0.f); o.y = fmaxf(o.y, 0.f);
            o.z = fmaxf(o.z, 0.f); o.w = fmaxf(o.w, 0.f);
            *(float4*)&out[(long long)(nb0 + v) * C_CH + 4 * c4] = o;
        }
    }
}

extern "C" void kernel_launch(void* const* d_in, const int* in_sizes, int n_in,
                              void* d_out, int out_size, void* d_ws, size_t ws_size,
                              hipStream_t stream) {
    const float* x  = (const float*)d_in[0];
    const int*   ei = (const int*)  d_in[1];
    const float* W  = (const float*)d_in[2];
    const float* b  = (const float*)d_in[3];
    float* out = (float*)d_out;

    const int N = in_sizes[0] / C_CH;
    const int E = in_sizes[1] / 2;
    const int* row = ei;        // edge_index[0]
    const int* col = ei + E;    // edge_index[1]
    const int nbuk = (N + BW - 1) >> BSH;   // 391 (<= MAXBUK)

    // Bucket capacity: mean bucket = E*BW/N ~ 2048, sd ~45; 4096 = huge margin.
    auto need = [&](int cap) {
        return (size_t)nbuk * cap * 4 + 128    // epk (+ overread slack)
             + (size_t)N * 4                   // dis
             + (((size_t)nbuk * 4 + 127) & ~(size_t)127)  // bcur (padded)
             + (size_t)(N + 1) * C_CH * 2;     // xsh incl. zero row
    };
    int cap = 4096;
    if (ws_size < need(4096)) cap = 2560;

    char* ws = (char*)d_ws;
    unsigned* epk = (unsigned*)ws;      ws += (size_t)nbuk * cap * 4 + 128;
    float* dis = (float*)ws;            ws += (size_t)N * 4;
    int* bcur = (int*)ws;               ws += ((size_t)nbuk * 4 + 127) & ~(size_t)127;
    __half* xsh = (__half*)ws;          // 8B-aligned for uint2 loads

    clearcur_kernel  <<<(nbuk + 255) / 256, 256, 0, stream>>>(bcur, nbuk);
    bin_kernel       <<<(E + BIN_CHUNK - 1) / BIN_CHUNK, 256, 0, stream>>>(row, col, bcur, epk, E, nbuk, cap);
    build_lite_kernel<<<nbuk, 256, 0, stream>>>(epk, bcur, x, dis, xsh, N, cap);
    gather_kernel    <<<nbuk, 512, 0, stream>>>((const uint2*)xsh, epk, bcur, dis,
                                                W, b, out, N, cap);
}

// Round 17
// 56.116 us; speedup vs baseline: 7.0929x; 7.0929x over previous
//
#include <hip/hip_runtime.h>
#include <hip/hip_fp16.h>

// GCN layer: out = relu( (D^-1/2 A D^-1/2 x) @ W + b )
// N=50000 nodes, E=800000 edges, C=64 channels, fp32 in/out.
//
// R17 = R14 (session-best 58.99us) + xsh 8B-alignment pad. R15/R16's LDS-atomic
// gather (sort-free) measured 365us — ds_add_f32 RMW serialization + bank
// conflicts make LDS accumulation ~15x worse than sorted-CSR plain reads.
//
// Build (rebuilt on-device every call; fixed-capacity bucket regions):
//   clearcur: bcur[] = 0 (tiny kernel — hipMemsetAsync's fill kernel showed
//             45us for 1.5KB in R13's trace; never memset tiny buffers)
//   bin:      per-block LDS histogram + per-edge local rank, one reservation
//             atomic per (block,bucket); writes packed (col_lo<<16|src) u32 at
//             bkt*cap + rel. BIN_CHUNK=2048 -> 391 blocks (occupancy).
//   build:    512 threads; per-bucket counting sort in LDS -> srcs with
//             8-ALIGNED PADDED per-node segments (pad slots = N -> zero row),
//             seg=(start,deg,dis_bits,0), xsh = half(dis*x); zero row xsh[N]
//   gather:   16-lane group per node, 32 nodes/block: per 8 edges one uint4
//             srcs load + 8 row loads in flight, no tail masks; per-thread
//             64x64 linear from LDS W + ReLU, float4 store.
// No float atomics anywhere.

#define C_CH 64
#define BW   128        // bucket width in nodes
#define BSH  7          // log2(BW)
#define MAXBUK 512      // >= ceil(N/BW) = 391
#define BIN_CHUNK 2048  // edges per bin block (391 blocks)
#define NPB  32         // nodes per gather block

// ---- clear bucket cursors ---------------------------------------------------
__global__ void clearcur_kernel(int* __restrict__ bcur, int nbuk) {
    int i = blockIdx.x * blockDim.x + threadIdx.x;
    if (i < nbuk) bcur[i] = 0;
}

// ---- bin: scatter edges into fixed-capacity bucket regions ------------------
__global__ void __launch_bounds__(256)
bin_kernel(const int* __restrict__ row, const int* __restrict__ col,
           int* __restrict__ bcur, unsigned* __restrict__ epk,
           int E, int nbuk, int cap) {
    __shared__ int h[MAXBUK];                 // block-local bucket counts
    __shared__ int rb[MAXBUK];                // block's reserved rel-base per bucket
    __shared__ unsigned short rank[BIN_CHUNK];// per-edge local rank
    int tid = threadIdx.x;
    int e0 = blockIdx.x * BIN_CHUNK;
    int cntE = E - e0; if (cntE > BIN_CHUNK) cntE = BIN_CHUNK;

    for (int i = tid; i < nbuk; i += 256) h[i] = 0;
    __syncthreads();

    const int4* col4 = (const int4*)(col + e0);   // e0 is 2048-aligned
    const int4* row4 = (const int4*)(row + e0);
    int cnt4 = cntE >> 2;
    for (int i = tid; i < cnt4; i += 256) {       // pass 1: ranks (int4 loads)
        int4 c = col4[i];
        rank[4*i+0] = (unsigned short)atomicAdd(&h[c.x >> BSH], 1);
        rank[4*i+1] = (unsigned short)atomicAdd(&h[c.y >> BSH], 1);
        rank[4*i+2] = (unsigned short)atomicAdd(&h[c.z >> BSH], 1);
        rank[4*i+3] = (unsigned short)atomicAdd(&h[c.w >> BSH], 1);
    }
    for (int i = (cnt4 << 2) + tid; i < cntE; i += 256)
        rank[i] = (unsigned short)atomicAdd(&h[col[e0 + i] >> BSH], 1);
    __syncthreads();

    for (int i = tid; i < nbuk; i += 256)         // 1 atomic/(block,bucket)
        rb[i] = h[i] ? atomicAdd(&bcur[i], h[i]) : 0;   // bcur starts at 0
    __syncthreads();

    for (int i = tid; i < cnt4; i += 256) {       // pass 2: write packed edges
        int4 c = col4[i];
        int4 r = row4[i];
        #pragma unroll
        for (int j = 0; j < 4; ++j) {
            int cc = (j == 0) ? c.x : (j == 1) ? c.y : (j == 2) ? c.z : c.w;
            int rr = (j == 0) ? r.x : (j == 1) ? r.y : (j == 2) ? r.z : r.w;
            int bkt = cc >> BSH;
            int rel = rb[bkt] + (int)rank[4*i+j];
            if (rel < cap)                        // safety clamp (never hit here)
                epk[bkt * cap + rel] = ((unsigned)(cc & (BW - 1)) << 16) | (unsigned)rr;
        }
    }
    for (int i = (cnt4 << 2) + tid; i < cntE; i += 256) {
        int cc = col[e0 + i];
        int bkt = cc >> BSH;
        int rel = rb[bkt] + (int)rank[i];
        if (rel < cap)
            epk[bkt * cap + rel] = ((unsigned)(cc & (BW - 1)) << 16) | (unsigned)row[e0 + i];
    }
}

// ---- build: per-bucket counting sort (8-aligned padded segments) ------------
__global__ void __launch_bounds__(512)
build_kernel(const unsigned* __restrict__ epk, const int* __restrict__ bcur,
             const float* __restrict__ x,
             int4* __restrict__ seg,              // (start, deg, dis_bits, 0)
             unsigned short* __restrict__ srcs, __half* __restrict__ xsh,
             int N, int cap) {
    __shared__ int cnt[BW];
    __shared__ int sc[BW];
    __shared__ int cur[BW];
    __shared__ float dv[BW];
    __shared__ int tot;
    __shared__ unsigned short sl[4096];           // cap <= 4096 always
    int tid = threadIdx.x;
    int b   = blockIdx.x;
    int base = b * cap;
    int cb = bcur[b]; if (cb > cap) cb = cap;     // bucket edge count
    int nb0 = b << BSH;
    int nn  = N - nb0; if (nn > BW) nn = BW;

    if (tid < BW) cnt[tid] = 0;
    for (int i = tid; i < cap; i += 512)          // prefill: pad slots -> zero row
        sl[i] = (unsigned short)N;
    __syncthreads();
    for (int i = tid; i < cb; i += 512)
        atomicAdd(&cnt[epk[base + i] >> 16], 1);
    __syncthreads();
    if (tid < BW) sc[tid] = (cnt[tid] + 7) & ~7;  // 8-padded degree
    __syncthreads();
    for (int off = 1; off < BW; off <<= 1) {      // inclusive scan of padded deg
        int t = (tid < BW && tid >= off) ? sc[tid - off] : 0;
        __syncthreads();
        if (tid < BW) sc[tid] += t;
        __syncthreads();
    }
    if (tid < BW) {
        int d  = cnt[tid];
        int dp = (d + 7) & ~7;
        int ex = sc[tid] - dp;                    // 8-aligned exclusive offset
        cur[tid] = ex;
        if (tid == BW - 1) tot = sc[tid];
        if (tid < nn) {
            float di = (d > 0) ? rsqrtf((float)d) : 0.0f;
            dv[tid] = di;
            seg[nb0 + tid] = make_int4(base + ex, d, __float_as_int(di), 0);
        }
    }
    __syncthreads();
    for (int i = tid; i < cb; i += 512) {         // scatter inside LDS
        unsigned p = epk[base + i];
        int pos = atomicAdd(&cur[p >> 16], 1);
        if (pos < cap) sl[pos] = (unsigned short)(p & 0xFFFFu);
    }
    __syncthreads();
    int cbp = tot; if (cbp > cap) cbp = cap;      // padded total (incl. N-fill)
    for (int i = tid; i < cbp; i += 512)          // coalesced copy out
        srcs[base + i] = sl[i];

    // xsh[n][c] = half(dis[n] * x[n][c]) for this bucket's nodes
    int tot2 = nn * (C_CH / 2);
    const float2* x2 = (const float2*)x;
    __half2* o2 = (__half2*)xsh;
    for (int i = tid; i < tot2; i += 512) {
        int nl = i >> 5;
        int c2 = i & 31;
        long long gi = (long long)(nb0 + nl) * (C_CH / 2) + c2;
        float2 v = x2[gi];
        float dn = dv[nl];
        o2[gi] = __floats2half2_rn(v.x * dn, v.y * dn);
    }
    // zero row at index N (gather's padding target)
    if (b == 0 && tid < C_CH / 2)
        o2[(long long)N * (C_CH / 2) + tid] = __floats2half2_rn(0.0f, 0.0f);
}

// ---- gather + aggregate + linear + ReLU (R8-proven form) ---------------------
// 16-lane group per node: lane c4 owns channels [4c4..4c4+3]. Per 8 edges:
// ONE uint4 load of 8 srcs (16B-aligned by construction) + 8 row-loads in
// flight; pad slots hold N -> zero row, so no masks anywhere. Linear:
// per-thread (node g, oc-quad c4), full-unroll kq (measured: no spill, R8/R9).
__global__ void __launch_bounds__(512)
gather_kernel(const uint2* __restrict__ xsh8,    // [(N+1)][16] x 8B
              const unsigned short* __restrict__ srcs,
              const int4* __restrict__ seg,      // (start, deg, dis_bits, 0)
              const float* __restrict__ W, const float* __restrict__ b,
              float* __restrict__ out, int N) {
    __shared__ float Ws[C_CH * C_CH];            // 16 KB
    __shared__ float bs[C_CH];
    __shared__ float ags[NPB][68];               // stride 68: conflict-free float4 rows

    int tid = threadIdx.x;
    {   // stage W as float4
        const float4* W4 = (const float4*)W;
        float4* Ws4 = (float4*)Ws;
        for (int i = tid; i < C_CH * C_CH / 4; i += 512) Ws4[i] = W4[i];
        if (tid < C_CH) bs[tid] = b[tid];
    }

    int g  = tid >> 4;        // group = local node 0..31
    int c4 = tid & 15;        // channel quad
    int t = blockIdx.x * NPB + g;

    if (t < N) {
        float4 acc = make_float4(0.f, 0.f, 0.f, 0.f);
        int4 sg = seg[t];                        // one 16B load: start, deg, dis
        int s0 = sg.x;                           // multiple of 8
        int degp = (sg.y + 7) & ~7;              // 8-padded degree
        for (int eb = 0; eb < degp; eb += 8) {
            uint4 sv = *(const uint4*)(srcs + s0 + eb);   // 8 srcs, one 16B load
            int r0 = (int)(sv.x & 0xFFFFu), r1 = (int)(sv.x >> 16);
            int r2 = (int)(sv.y & 0xFFFFu), r3 = (int)(sv.y >> 16);
            int r4 = (int)(sv.z & 0xFFFFu), r5 = (int)(sv.z >> 16);
            int r6 = (int)(sv.w & 0xFFFFu), r7 = (int)(sv.w >> 16);
            uint2 u0 = xsh8[r0 * 16 + c4];       // 8 independent loads in flight
            uint2 u1 = xsh8[r1 * 16 + c4];
            uint2 u2 = xsh8[r2 * 16 + c4];
            uint2 u3 = xsh8[r3 * 16 + c4];
            uint2 u4 = xsh8[r4 * 16 + c4];
            uint2 u5 = xsh8[r5 * 16 + c4];
            uint2 u6 = xsh8[r6 * 16 + c4];
            uint2 u7 = xsh8[r7 * 16 + c4];
            #pragma unroll
            for (int k = 0; k < 8; ++k) {
                uint2 u = (k==0)?u0:(k==1)?u1:(k==2)?u2:(k==3)?u3:
                          (k==4)?u4:(k==5)?u5:(k==6)?u6:u7;
                float2 f0 = __half22float2(*(__half2*)&u.x);
                float2 f1 = __half22float2(*(__half2*)&u.y);
                acc.x += f0.x; acc.y += f0.y; acc.z += f1.x; acc.w += f1.y;
            }
        }
        float dt = __int_as_float(sg.z);
        acc.x *= dt; acc.y *= dt; acc.z *= dt; acc.w *= dt;
        *(float4*)&ags[g][4 * c4] = acc;
    }
    __syncthreads();

    // linear: same thread mapping (node g, oc-quad c4), k blocked by 4
    if (t < N) {
        float4 o = *(const float4*)&bs[4 * c4];
        #pragma unroll
        for (int kq = 0; kq < C_CH / 4; ++kq) {
            float4 a4 = *(const float4*)&ags[g][4 * kq];
            float4 w0 = *(const float4*)&Ws[(4 * kq + 0) * C_CH + 4 * c4];
            float4 w1 = *(const float4*)&Ws[(4 * kq + 1) * C_CH + 4 * c4];
            float4 w2 = *(const float4*)&Ws[(4 * kq + 2) * C_CH + 4 * c4];
            float4 w3 = *(const float4*)&Ws[(4 * kq + 3) * C_CH + 4 * c4];
            o.x = fmaf(a4.x, w0.x, o.x); o.y = fmaf(a4.x, w0.y, o.y);
            o.z = fmaf(a4.x, w0.z, o.z); o.w = fmaf(a4.x, w0.w, o.w);
            o.x = fmaf(a4.y, w1.x, o.x); o.y = fmaf(a4.y, w1.y, o.y);
            o.z = fmaf(a4.y, w1.z, o.z); o.w = fmaf(a4.y, w1.w, o.w);
            o.x = fmaf(a4.z, w2.x, o.x); o.y = fmaf(a4.z, w2.y, o.y);
            o.z = fmaf(a4.z, w2.z, o.z); o.w = fmaf(a4.z, w2.w, o.w);
            o.x = fmaf(a4.w, w3.x, o.x); o.y = fmaf(a4.w, w3.y, o.y);
            o.z = fmaf(a4.w, w3.z, o.z); o.w = fmaf(a4.w, w3.w, o.w);
        }
        o.x = fmaxf(o.x, 0.f); o.y = fmaxf(o.y, 0.f);
        o.z = fmaxf(o.z, 0.f); o.w = fmaxf(o.w, 0.f);
        *(float4*)&out[(long long)t * C_CH + 4 * c4] = o;   // 256B/group, coalesced
    }
}

extern "C" void kernel_launch(void* const* d_in, const int* in_sizes, int n_in,
                              void* d_out, int out_size, void* d_ws, size_t ws_size,
                              hipStream_t stream) {
    const float* x  = (const float*)d_in[0];
    const int*   ei = (const int*)  d_in[1];
    const float* W  = (const float*)d_in[2];
    const float* b  = (const float*)d_in[3];
    float* out = (float*)d_out;

    const int N = in_sizes[0] / C_CH;
    const int E = in_sizes[1] / 2;
    const int* row = ei;        // edge_index[0]
    const int* col = ei + E;    // edge_index[1]
    const int nbuk = (N + BW - 1) >> BSH;   // 391 (<= MAXBUK)

    // Bucket capacity: mean bucket = E*BW/N ~ 2048, 8-padded +<=448 worst;
    // 4096 gives >40 sigma headroom. Fallback 3072.
    auto need = [&](int cap) {
        return (size_t)nbuk * cap * 6          // epk (4B) + srcs (2B)
             + (size_t)N * 16 + 256            // seg int4
             + (((size_t)nbuk * 4 + 127) & ~(size_t)127)  // bcur (padded)
             + (size_t)(N + 1) * C_CH * 2;     // xsh incl. zero row
    };
    int cap = 4096;
    if (ws_size < need(4096)) cap = 3072;

    char* ws = (char*)d_ws;
    unsigned* epk = (unsigned*)ws;      ws += (size_t)nbuk * cap * 4;
    unsigned short* srcs = (unsigned short*)ws;  ws += (size_t)nbuk * cap * 2;
    int4* seg = (int4*)ws;              ws += (size_t)N * 16;
    int* bcur = (int*)ws;               ws += ((size_t)nbuk * 4 + 127) & ~(size_t)127;
    __half* xsh = (__half*)ws;          // 8B-aligned for uint2 loads

    clearcur_kernel<<<(nbuk + 255) / 256, 256, 0, stream>>>(bcur, nbuk);
    bin_kernel <<<(E + BIN_CHUNK - 1) / BIN_CHUNK, 256, 0, stream>>>(row, col, bcur, epk, E, nbuk, cap);
    build_kernel<<<nbuk, 512, 0, stream>>>(epk, bcur, x, seg, srcs, xsh, N, cap);
    gather_kernel<<<(N + NPB - 1) / NPB, 512, 0, stream>>>((const uint2*)xsh, srcs, seg,
                                                           W, b, out, N);
}